// Round 2
// baseline (350.845 us; speedup 1.0000x reference)
//
#include <hip/hip_runtime.h>

// Problem constants from setup_inputs(): B=8, N=8192, D=512, fp32 in/out.
#define DIM 512
#define NPB 8192   // rows per batch (N)
#define CHUNK 8    // consecutive rows owned by each wave

typedef float f4 __attribute__((ext_vector_type(4)));

__device__ __forceinline__ float dot4(f4 u, f4 v) {
    f4 p = u * v;
    return p.x + p.y + p.z + p.w;
}

// Persistent waves; wave w owns CHUNK consecutive rows (contiguous 16 KB
// window per tensor -> DRAM page locality). 1-row software pipeline: loads
// for row r+1 issue before the shuffle reduction of row r.
// R1 change: plain (cacheable) loads instead of __builtin_nontemporal_load —
// testing the theory that the nt cache-bypass bit was throttling HBM
// efficiency to ~20% of peak (1.26 TB/s observed vs 6.3 TB/s achievable).
__global__ __launch_bounds__(256) void disc_kernel(
    const float* __restrict__ s,
    const float* __restrict__ hrl,
    const float* __restrict__ hfk,
    float* __restrict__ out,
    int n_rows) {
    int wave = (blockIdx.x * blockDim.x + threadIdx.x) >> 6;
    int lane = threadIdx.x & 63;

    int row0 = wave * CHUNK;
    if (row0 >= n_rows) return;

    const f4* sp = (const f4*)(s   + (size_t)row0 * DIM);
    const f4* ap = (const f4*)(hrl + (size_t)row0 * DIM);
    const f4* bp = (const f4*)(hfk + (size_t)row0 * DIM);

    // Preload row0: 6 x float4 per lane ([lane] and [lane+64] of each tensor).
    f4 s0 = sp[lane], s1 = sp[lane + 64];
    f4 a0 = ap[lane], a1 = ap[lane + 64];
    f4 b0 = bp[lane], b1 = bp[lane + 64];

    #pragma unroll
    for (int i = 0; i < CHUNK; ++i) {
        int row = row0 + i;
        if (row >= n_rows) break;

        f4 t0, t1, u0, u1, v0, v1;
        if (i + 1 < CHUNK && row + 1 < n_rows) {
            // Next row is 128 float4 further along the same contiguous window.
            const f4* spn = sp + (size_t)(i + 1) * (DIM / 4);
            const f4* apn = ap + (size_t)(i + 1) * (DIM / 4);
            const f4* bpn = bp + (size_t)(i + 1) * (DIM / 4);
            t0 = spn[lane]; t1 = spn[lane + 64];
            u0 = apn[lane]; u1 = apn[lane + 64];
            v0 = bpn[lane]; v1 = bpn[lane + 64];
        }

        float ss = dot4(s0, s0) + dot4(s1, s1);
        float aa = dot4(a0, a0) + dot4(a1, a1);
        float bb = dot4(b0, b0) + dot4(b1, b1);
        float sa = dot4(s0, a0) + dot4(s1, a1);
        float sb = dot4(s0, b0) + dot4(s1, b1);

        // Wave-64 butterfly; next row's loads are in flight during this chain.
        #pragma unroll
        for (int off = 32; off > 0; off >>= 1) {
            ss += __shfl_xor(ss, off, 64);
            aa += __shfl_xor(aa, off, 64);
            bb += __shfl_xor(bb, off, 64);
            sa += __shfl_xor(sa, off, 64);
            sb += __shfl_xor(sb, off, 64);
        }

        if (lane == 0) {
            const float eps = 1e-12f;
            float ns = fmaxf(sqrtf(ss), eps);
            float na = fmaxf(sqrtf(aa), eps);
            float nb = fmaxf(sqrtf(bb), eps);
            int bidx = row >> 13;          // row / 8192
            int n    = row & (NPB - 1);
            size_t obase = (size_t)bidx * (2 * NPB) + n;
            out[obase]       = sa / (ns * na);   // sc_rl
            out[obase + NPB] = sb / (ns * nb);   // sc_fk
        }

        // Rotate pipeline registers.
        s0 = t0; s1 = t1; a0 = u0; a1 = u1; b0 = v0; b1 = v1;
    }
}

extern "C" void kernel_launch(void* const* d_in, const int* in_sizes, int n_in,
                              void* d_out, int out_size, void* d_ws, size_t ws_size,
                              hipStream_t stream) {
    const float* s   = (const float*)d_in[0];
    const float* hrl = (const float*)d_in[1];
    const float* hfk = (const float*)d_in[2];
    float* out = (float*)d_out;

    int n_rows = in_sizes[0] / DIM;            // B*N = 65536
    int threads = 256;                         // 4 waves/block
    int waves_needed = (n_rows + CHUNK - 1) / CHUNK;        // 8192
    int blocks = (waves_needed + (threads / 64) - 1) / (threads / 64);  // 2048

    disc_kernel<<<blocks, threads, 0, stream>>>(s, hrl, hfk, out, n_rows);
}

// Round 3
// 343.478 us; speedup vs baseline: 1.0214x; 1.0214x over previous
//
#include <hip/hip_runtime.h>

// Problem constants from setup_inputs(): B=8, N=8192, D=512, fp32 in/out.
#define DIM 512
#define NPB 8192   // rows per batch (N)

typedef float f4 __attribute__((ext_vector_type(4)));

__device__ __forceinline__ float dot4(f4 u, f4 v) {
    f4 p = u * v;
    return p.x + p.y + p.z + p.w;
}

// R2 redesign: one row per wave, dense sweep.
// Previous design gave each persistent wave a private 16 KB window per tensor
// (8192 waves x 3 tensors ~ 24k concurrent DRAM streams) -> HBM row-buffer
// thrash, measured 1.54 TB/s effective HBM BW (24% of achievable) and
// dur ~= FETCH_SIZE / 1.54 TB/s. Here wave g reads row g once: resident
// blocks cover a dense moving band of rows, so the aggregate traffic is a
// linear sweep of all three tensors (copy-like), which is the access shape
// that hits ~6.3 TB/s on this chip. Latency is hidden by block churn
// (64 blocks/CU queued), not software pipelining.
__global__ __launch_bounds__(256) void disc_kernel(
    const float* __restrict__ s,
    const float* __restrict__ hrl,
    const float* __restrict__ hfk,
    float* __restrict__ out,
    int n_rows) {
    int row  = (blockIdx.x * blockDim.x + threadIdx.x) >> 6;  // 1 wave = 1 row
    int lane = threadIdx.x & 63;
    if (row >= n_rows) return;

    size_t base = (size_t)row * DIM;
    const f4* sp = (const f4*)(s   + base);
    const f4* ap = (const f4*)(hrl + base);
    const f4* bp = (const f4*)(hfk + base);

    // 6 x 1KB coalesced loads: [lane] covers floats 0..255, [lane+64] 256..511.
    f4 s0 = sp[lane], s1 = sp[lane + 64];
    f4 a0 = ap[lane], a1 = ap[lane + 64];
    f4 b0 = bp[lane], b1 = bp[lane + 64];

    float ss = dot4(s0, s0) + dot4(s1, s1);
    float aa = dot4(a0, a0) + dot4(a1, a1);
    float bb = dot4(b0, b0) + dot4(b1, b1);
    float sa = dot4(s0, a0) + dot4(s1, a1);
    float sb = dot4(s0, b0) + dot4(s1, b1);

    // Wave-64 butterfly reduction.
    #pragma unroll
    for (int off = 32; off > 0; off >>= 1) {
        ss += __shfl_xor(ss, off, 64);
        aa += __shfl_xor(aa, off, 64);
        bb += __shfl_xor(bb, off, 64);
        sa += __shfl_xor(sa, off, 64);
        sb += __shfl_xor(sb, off, 64);
    }

    if (lane == 0) {
        const float eps = 1e-12f;
        float ns = fmaxf(sqrtf(ss), eps);
        float na = fmaxf(sqrtf(aa), eps);
        float nb = fmaxf(sqrtf(bb), eps);
        int bidx = row >> 13;          // row / 8192
        int n    = row & (NPB - 1);
        size_t obase = (size_t)bidx * (2 * NPB) + n;
        out[obase]       = sa / (ns * na);   // sc_rl
        out[obase + NPB] = sb / (ns * nb);   // sc_fk
    }
}

extern "C" void kernel_launch(void* const* d_in, const int* in_sizes, int n_in,
                              void* d_out, int out_size, void* d_ws, size_t ws_size,
                              hipStream_t stream) {
    const float* s   = (const float*)d_in[0];
    const float* hrl = (const float*)d_in[1];
    const float* hfk = (const float*)d_in[2];
    float* out = (float*)d_out;

    int n_rows = in_sizes[0] / DIM;            // B*N = 65536
    int threads = 256;                         // 4 waves/block = 4 rows/block
    int blocks = (n_rows + 3) / 4;             // 16384
    disc_kernel<<<blocks, threads, 0, stream>>>(s, hrl, hfk, out, n_rows);
}